// Round 8
// baseline (1097.735 us; speedup 1.0000x reference)
//
#include <hip/hip_runtime.h>
#include <cstdint>

typedef _Float16 f16x2 __attribute__((ext_vector_type(2)));

// Clamp-free fast activations: gate pre-activations are provably |x| <~ 15
// here (0.1-scale weights, |h|<=1), far from fp32 exp overflow.
__device__ __forceinline__ float fsig(float x) {
  return __fdividef(1.f, 1.f + __expf(-x));
}
__device__ __forceinline__ float ftanh_(float x) {
  return fmaf(2.f, fsig(x + x), -1.f);
}
__device__ __forceinline__ int packf16(float a, float b) {
  f16x2 p; p.x = (_Float16)a; p.y = (_Float16)b;
  return __builtin_bit_cast(int, p);
}
__device__ __forceinline__ float dot2(int w, int h, float acc) {
  return __builtin_amdgcn_fdot2(__builtin_bit_cast(f16x2, w),
                                __builtin_bit_cast(f16x2, h), acc, false);
}
template <int PAT>
__device__ __forceinline__ float swzf(float v) {
  return __int_as_float(__builtin_amdgcn_ds_swizzle(__float_as_int(v), PAT));
}
#define SWZ_X1 0x041F  // xor lane^1 (BitMode, intra-32-lane: octets never cross)
#define SWZ_X2 0x081F  // xor lane^2
#define SWZ_X4 0x101F  // xor lane^4

// ---------------------------------------------------------------------------
// Layer 1: 262144 independent LSTM chains, seq=16, input=1, hidden=8.
// R6 structure (best measured: ~129 us): one chain/thread, weights f16-packed
// into pinned VGPRs, dot2 h-part, rolled t-loop, x prefetched. Activations
// now clamp-free.
// ---------------------------------------------------------------------------
__global__ __launch_bounds__(256, 2) void lstm1_kernel(
    const float* __restrict__ x, const float* __restrict__ Wih,
    const float* __restrict__ Whh, const float* __restrict__ bih,
    const float* __restrict__ bhh, int4* __restrict__ h1out) {
  const int n = blockIdx.x * 256 + threadIdx.x;  // chain id = b*S + s

  int whh2[128];  // whh2[r*4+j] = (Whh[r][2j], Whh[r][2j+1])
#pragma unroll
  for (int r = 0; r < 32; ++r) {
#pragma unroll
    for (int j = 0; j < 4; ++j) {
      float2 v = ((const float2*)(Whh + r * 8))[j];
      whh2[r * 4 + j] = packf16(v.x, v.y);
    }
  }
  int wxb[32];  // (Wih[r], bih[r]+bhh[r]); dotted with (x_t, 1)
#pragma unroll
  for (int r = 0; r < 32; ++r) wxb[r] = packf16(Wih[r], bih[r] + bhh[r]);

#pragma unroll
  for (int i = 0; i < 128; i += 8)
    asm volatile("" : "+v"(whh2[i]), "+v"(whh2[i + 1]), "+v"(whh2[i + 2]),
                      "+v"(whh2[i + 3]), "+v"(whh2[i + 4]), "+v"(whh2[i + 5]),
                      "+v"(whh2[i + 6]), "+v"(whh2[i + 7]));
#pragma unroll
  for (int i = 0; i < 32; i += 8)
    asm volatile("" : "+v"(wxb[i]), "+v"(wxb[i + 1]), "+v"(wxb[i + 2]),
                      "+v"(wxb[i + 3]), "+v"(wxb[i + 4]), "+v"(wxb[i + 5]),
                      "+v"(wxb[i + 6]), "+v"(wxb[i + 7]));

  const float* __restrict__ xp = x + (size_t)n * 16;
  float c[8];
  int h2[4];  // h as 4 packed f16 pairs
#pragma unroll
  for (int k = 0; k < 8; ++k) c[k] = 0.f;
#pragma unroll
  for (int j = 0; j < 4; ++j) h2[j] = 0;

  float xv = xp[0];
#pragma unroll 1
  for (int t = 0; t < 16; ++t) {
    float xn = xp[(t + 1) & 15];  // prefetch (wraps harmlessly at t=15)
    const int xt1 = packf16(xv, 1.f);
    float hn[8];
#pragma unroll
    for (int k = 0; k < 8; ++k) {
      float acc[4];
#pragma unroll
      for (int gi = 0; gi < 4; ++gi) {
        const int r = gi * 8 + k;
        float a = dot2(wxb[r], xt1, 0.f);
        a = dot2(whh2[r * 4 + 0], h2[0], a);
        a = dot2(whh2[r * 4 + 1], h2[1], a);
        a = dot2(whh2[r * 4 + 2], h2[2], a);
        a = dot2(whh2[r * 4 + 3], h2[3], a);
        acc[gi] = a;
      }
      float iv = fsig(acc[0]), fv = fsig(acc[1]);
      float gv = ftanh_(acc[2]), ov = fsig(acc[3]);
      c[k] = fmaf(fv, c[k], iv * gv);
      hn[k] = ov * ftanh_(c[k]);
    }
#pragma unroll
    for (int j = 0; j < 4; ++j) h2[j] = packf16(hn[2 * j], hn[2 * j + 1]);
    xv = xn;
  }
  int4 o;
  o.x = h2[0]; o.y = h2[1]; o.z = h2[2]; o.w = h2[3];
  h1out[n] = o;
}

// ---------------------------------------------------------------------------
// Layer 2: B=256 recurrences -> 1 block (1024 thr, 16 waves) per CU.
// EIGHTH K-SPLIT: thread (m = t>>3, q = t&7) holds K-eighth q (16 elems) of
// ALL FOUR gate rows of hidden index m (32 pinned half2) and an eighth of h
// (8 regs, 2 ds_read_b128 refresh). R7 evidence: per-step cyc (1858) is ~75%
// stall at 2 waves/SIMD — latency-bound, not pipe-bound. 4 waves/SIMD halves
// per-wave work and doubles chain overlap. Reduce: 5 ds_swizzle hops
// (xor1/xor2/xor4, intra-octet); gather: 3 swizzles + selects; c/h updated
// redundantly per octet. ONE barrier/step, 512 B double-buffered sH.
// ---------------------------------------------------------------------------
__global__ __launch_bounds__(1024, 4) void lstm2_kernel(
    const int4* __restrict__ h1, const float* __restrict__ Wih,
    const float* __restrict__ Whh, const float* __restrict__ bih,
    const float* __restrict__ bhh, const float* __restrict__ Wd1,
    const float* __restrict__ bd1, const float* __restrict__ Wd2,
    const float* __restrict__ bd2, float* __restrict__ out) {
  __shared__ __align__(16) _Float16 sH[2][128];  // 512 B double-buffered h
  const int b = blockIdx.x;
  const int t = threadIdx.x;
  const int m = t >> 3;            // hidden index 0..127
  const int q = t & 7;             // K-eighth / reduce slot
  const int G = 2 * (q & 1) + ((q >> 1) & 1);  // gate this thread finalizes
  const bool selA = (q & 1) != 0;  // G bit1
  const bool selB = (q & 2) != 0;  // G bit0
  const bool is_tanh = ((q & 3) == 1);  // G == 2
  const bool is_wr = (q == 0);

  // K-eighth q of all four gate rows of index m: w[g*8+j]
  int w[32];
#pragma unroll
  for (int g = 0; g < 4; ++g) {
    const float2* p = (const float2*)(Whh + (size_t)(g * 128 + m) * 128 + q * 16);
#pragma unroll
    for (int j = 0; j < 8; ++j) {
      float2 v = p[j];
      w[g * 8 + j] = packf16(v.x, v.y);
    }
  }
#pragma unroll
  for (int i = 0; i < 32; i += 8)
    asm volatile("" : "+v"(w[i]), "+v"(w[i + 1]), "+v"(w[i + 2]),
                      "+v"(w[i + 3]), "+v"(w[i + 4]), "+v"(w[i + 5]),
                      "+v"(w[i + 6]), "+v"(w[i + 7]));

  // x-row + bias for gate row G*128+m
  int wig[4];
  {
    const float2* pi = (const float2*)(Wih + (size_t)(G * 128 + m) * 8);
#pragma unroll
    for (int j = 0; j < 4; ++j) {
      float2 v = pi[j];
      wig[j] = packf16(v.x, v.y);
    }
  }
  asm volatile("" : "+v"(wig[0]), "+v"(wig[1]), "+v"(wig[2]), "+v"(wig[3]));
  const float bias = bih[G * 128 + m] + bhh[G * 128 + m];

  int hq[8];  // this thread's h-eighth (16 f16)
#pragma unroll
  for (int i = 0; i < 8; ++i) hq[i] = 0;
  float c = 0.f;  // cell state for index m (replicated across the octet)

  const int4* __restrict__ xq = h1 + (size_t)b * 1024;  // 8 f16 per step
  int4 xc = xq[0];  // uniform -> s_load

#pragma unroll 1
  for (int ts = 0; ts < 1024; ++ts) {
    int4 xn = xq[(ts + 1) & 1023];  // prefetch (wraps harmlessly)

    // x-part + bias for this thread's final gate
    float bx = bias;
    bx = dot2(wig[0], xc.x, bx);
    bx = dot2(wig[1], xc.y, bx);
    bx = dot2(wig[2], xc.z, bx);
    bx = dot2(wig[3], xc.w, bx);

    // eighth-dots of all 4 gate rows (32 dot2, 4 independent chains)
    float R0 = 0.f, R1 = 0.f, R2 = 0.f, R3 = 0.f;
#pragma unroll
    for (int j = 0; j < 8; ++j) {
      R0 = dot2(w[j], hq[j], R0);
      R1 = dot2(w[8 + j], hq[j], R1);
      R2 = dot2(w[16 + j], hq[j], R2);
      R3 = dot2(w[24 + j], hq[j], R3);
    }
    // transpose-reduce across the octet -> thread q holds gate G's full sum
    // Phase A (xor1): even keeps (R0,R1) sends (R2,R3); odd the reverse.
    float sA0 = selA ? R0 : R2, sA1 = selA ? R1 : R3;
    float kA0 = selA ? R2 : R0, kA1 = selA ? R3 : R1;
    float A0 = kA0 + swzf<SWZ_X1>(sA0);  // gate 2*selA + 0
    float A1 = kA1 + swzf<SWZ_X1>(sA1);  // gate 2*selA + 1
    // Phase B (xor2): keep A0 if !selB else A1; partner (same selA) sends other
    float sB = selB ? A0 : A1;
    float kB = selB ? A1 : A0;
    float S = kB + swzf<SWZ_X2>(sB);     // gate G, half-K
    // Phase C (xor4): partner holds same gate over the other K-half
    S = S + swzf<SWZ_X4>(S) + bx;

    // activation (tanh iff G==2), via 2*sig(2x)-1
    float u = is_tanh ? (S + S) : S;
    float sg = fsig(u);
    float act = is_tanh ? fmaf(2.f, sg, -1.f) : sg;

    // gather all 4 gates: tags {act:G, v1:G^2, v2:G^1, v3:G^3}
    float v1 = swzf<SWZ_X1>(act);
    float v2 = swzf<SWZ_X2>(act);
    float v3 = swzf<SWZ_X2>(v1);
    float iv = selB ? (selA ? v3 : v2) : (selA ? v1 : act);   // gate 0
    float fv = selB ? (selA ? v1 : act) : (selA ? v3 : v2);   // gate 1
    float gv = selB ? (selA ? v2 : v3) : (selA ? act : v1);   // gate 2
    float ov = selB ? (selA ? act : v1) : (selA ? v2 : v3);   // gate 3

    c = fmaf(fv, c, iv * gv);
    float hx = ov * ftanh_(c);
    if (is_wr) sH[ts & 1][m] = (_Float16)hx;  // one writer per index
    __syncthreads();                          // the only barrier per step

    {  // refresh h-eighth: 2 x ds_read_b128 (8-way same-addr broadcast,
       // 8 distinct 16B lines per instr -> all 32 banks hit once: conflict-free)
      const int4* src = (const int4*)(&sH[ts & 1][q * 16]);
      int4 A = src[0], B = src[1];
      hq[0] = A.x; hq[1] = A.y; hq[2] = A.z; hq[3] = A.w;
      hq[4] = B.x; hq[5] = B.y; hq[6] = B.z; hq[7] = B.w;
    }
    xc = xn;
  }

  // Epilogue: out[b] = (h @ Wd1.T + bd1) @ Wd2.T + bd2; h_T is in sH[1].
  if (t < 64) {
    float a = bd1[t];
#pragma unroll
    for (int k = 0; k < 128; ++k)
      a = fmaf(Wd1[t * 128 + k], (float)sH[1][k], a);
    float v = a * Wd2[t];
#pragma unroll
    for (int off = 32; off > 0; off >>= 1) v += __shfl_down(v, off);
    if (t == 0) out[b] = v + bd2[0];
  }
}

extern "C" void kernel_launch(void* const* d_in, const int* in_sizes, int n_in,
                              void* d_out, int out_size, void* d_ws, size_t ws_size,
                              hipStream_t stream) {
  const float* x    = (const float*)d_in[0];
  // d_in[1] is the unused python scalar `data`
  const float* Wih1 = (const float*)d_in[2];
  const float* Whh1 = (const float*)d_in[3];
  const float* bih1 = (const float*)d_in[4];
  const float* bhh1 = (const float*)d_in[5];
  const float* Wih2 = (const float*)d_in[6];
  const float* Whh2 = (const float*)d_in[7];
  const float* bih2 = (const float*)d_in[8];
  const float* bhh2 = (const float*)d_in[9];
  const float* W1   = (const float*)d_in[10];
  const float* b1   = (const float*)d_in[11];
  const float* W2   = (const float*)d_in[12];
  const float* b2   = (const float*)d_in[13];
  float* out = (float*)d_out;

  int4* h1 = (int4*)d_ws;  // 262144 chains x 8 f16 = 4 MB scratch

  lstm1_kernel<<<1024, 256, 0, stream>>>(x, Wih1, Whh1, bih1, bhh1, h1);
  lstm2_kernel<<<256, 1024, 0, stream>>>(h1, Wih2, Whh2, bih2, bhh2,
                                         W1, b1, W2, b2, out);
}

// Round 9
// 901.757 us; speedup vs baseline: 1.2173x; 1.2173x over previous
//
#include <hip/hip_runtime.h>
#include <cstdint>

typedef _Float16 f16x2 __attribute__((ext_vector_type(2)));

// Clamp-free fast activations: gate pre-activations are provably |x| <~ 15
// here (0.1-scale weights, |h|<=1), far from fp32 exp overflow.
__device__ __forceinline__ float fsig(float x) {
  return __fdividef(1.f, 1.f + __expf(-x));
}
__device__ __forceinline__ float ftanh_(float x) {
  return fmaf(2.f, fsig(x + x), -1.f);
}
__device__ __forceinline__ int packf16(float a, float b) {
  f16x2 p; p.x = (_Float16)a; p.y = (_Float16)b;
  return __builtin_bit_cast(int, p);
}
__device__ __forceinline__ float dot2(int w, int h, float acc) {
  return __builtin_amdgcn_fdot2(__builtin_bit_cast(f16x2, w),
                                __builtin_bit_cast(f16x2, h), acc, false);
}
template <int PAT>
__device__ __forceinline__ float swzf(float v) {
  return __int_as_float(__builtin_amdgcn_ds_swizzle(__float_as_int(v), PAT));
}
#define SWZ_X1 0x041F  // xor lane^1 (BitMode)
#define SWZ_X2 0x081F  // xor lane^2

// ---------------------------------------------------------------------------
// Layer 1: unchanged from R8 (~75 us) to isolate the lstm2 experiment.
// NOTE: still contains asm pins; if the lstm2 AGPR theory validates, R10
// applies the same de-pinning here.
// ---------------------------------------------------------------------------
__global__ __launch_bounds__(256, 2) void lstm1_kernel(
    const float* __restrict__ x, const float* __restrict__ Wih,
    const float* __restrict__ Whh, const float* __restrict__ bih,
    const float* __restrict__ bhh, int4* __restrict__ h1out) {
  const int n = blockIdx.x * 256 + threadIdx.x;  // chain id = b*S + s

  int whh2[128];  // whh2[r*4+j] = (Whh[r][2j], Whh[r][2j+1])
#pragma unroll
  for (int r = 0; r < 32; ++r) {
#pragma unroll
    for (int j = 0; j < 4; ++j) {
      float2 v = ((const float2*)(Whh + r * 8))[j];
      whh2[r * 4 + j] = packf16(v.x, v.y);
    }
  }
  int wxb[32];  // (Wih[r], bih[r]+bhh[r]); dotted with (x_t, 1)
#pragma unroll
  for (int r = 0; r < 32; ++r) wxb[r] = packf16(Wih[r], bih[r] + bhh[r]);

#pragma unroll
  for (int i = 0; i < 128; i += 8)
    asm volatile("" : "+v"(whh2[i]), "+v"(whh2[i + 1]), "+v"(whh2[i + 2]),
                      "+v"(whh2[i + 3]), "+v"(whh2[i + 4]), "+v"(whh2[i + 5]),
                      "+v"(whh2[i + 6]), "+v"(whh2[i + 7]));
#pragma unroll
  for (int i = 0; i < 32; i += 8)
    asm volatile("" : "+v"(wxb[i]), "+v"(wxb[i + 1]), "+v"(wxb[i + 2]),
                      "+v"(wxb[i + 3]), "+v"(wxb[i + 4]), "+v"(wxb[i + 5]),
                      "+v"(wxb[i + 6]), "+v"(wxb[i + 7]));

  const float* __restrict__ xp = x + (size_t)n * 16;
  float c[8];
  int h2[4];  // h as 4 packed f16 pairs
#pragma unroll
  for (int k = 0; k < 8; ++k) c[k] = 0.f;
#pragma unroll
  for (int j = 0; j < 4; ++j) h2[j] = 0;

  float xv = xp[0];
#pragma unroll 1
  for (int t = 0; t < 16; ++t) {
    float xn = xp[(t + 1) & 15];  // prefetch (wraps harmlessly at t=15)
    const int xt1 = packf16(xv, 1.f);
    float hn[8];
#pragma unroll
    for (int k = 0; k < 8; ++k) {
      float acc[4];
#pragma unroll
      for (int gi = 0; gi < 4; ++gi) {
        const int r = gi * 8 + k;
        float a = dot2(wxb[r], xt1, 0.f);
        a = dot2(whh2[r * 4 + 0], h2[0], a);
        a = dot2(whh2[r * 4 + 1], h2[1], a);
        a = dot2(whh2[r * 4 + 2], h2[2], a);
        a = dot2(whh2[r * 4 + 3], h2[3], a);
        acc[gi] = a;
      }
      float iv = fsig(acc[0]), fv = fsig(acc[1]);
      float gv = ftanh_(acc[2]), ov = fsig(acc[3]);
      c[k] = fmaf(fv, c[k], iv * gv);
      hn[k] = ov * ftanh_(c[k]);
    }
#pragma unroll
    for (int j = 0; j < 4; ++j) h2[j] = packf16(hn[2 * j], hn[2 * j + 1]);
    xv = xn;
  }
  int4 o;
  o.x = h2[0]; o.y = h2[1]; o.z = h2[2]; o.w = h2[3];
  h1out[n] = o;
}

// ---------------------------------------------------------------------------
// Layer 2: R7 quad-split structure, ALL ASM PINS REMOVED (sole change).
// Theory: inline asm (even empty pins) disables LLVM's amdgpu-no-agpr
// inference; the allocator then parks long-lived weights in AGPRs and
// inserts v_accvgpr_read before every use — the consistent ~2.5x VALU
// bloat of R4..R8 and the absurd VGPR_Count=36..84 readings. With no asm
// in the function, AGPRs are off-limits and weights must be real VGPRs
// (~115 live values, fits the 256 budget at (512,2); pressure low enough
// that R3-style load-sinking should not trigger).
// ---------------------------------------------------------------------------
__global__ __launch_bounds__(512, 2) void lstm2_kernel(
    const int4* __restrict__ h1, const float* __restrict__ Wih,
    const float* __restrict__ Whh, const float* __restrict__ bih,
    const float* __restrict__ bhh, const float* __restrict__ Wd1,
    const float* __restrict__ bd1, const float* __restrict__ Wd2,
    const float* __restrict__ bd2, float* __restrict__ out) {
  __shared__ __align__(16) _Float16 sH[2][128];  // 512 B double-buffered h
  const int b = blockIdx.x;
  const int t = threadIdx.x;
  const int m = t >> 2;  // hidden index
  const int q = t & 3;   // K-quarter and result slot
  const int G = ((q & 1) << 1) | (q >> 1);  // gate this thread finalizes
  const bool sel0 = (q & 1) != 0;
  const bool sel1 = (q & 2) != 0;
  const bool isq0 = (q == 0);
  const bool isq1 = (q == 1);  // G==2 (tanh gate)

  // K-quarter q of all four gate rows of index m: w[g*16+j]
  int w[64];
#pragma unroll
  for (int g = 0; g < 4; ++g) {
    const float2* p = (const float2*)(Whh + (size_t)(g * 128 + m) * 128 + q * 32);
#pragma unroll
    for (int j = 0; j < 16; ++j) {
      float2 v = p[j];
      w[g * 16 + j] = packf16(v.x, v.y);
    }
  }

  // x-row + bias for the gate this thread finalizes (row G*128+m)
  int wig[4];
  {
    const float2* pi = (const float2*)(Wih + (size_t)(G * 128 + m) * 8);
#pragma unroll
    for (int j = 0; j < 4; ++j) {
      float2 v = pi[j];
      wig[j] = packf16(v.x, v.y);
    }
  }
  const float bias = bih[G * 128 + m] + bhh[G * 128 + m];

  int hq[16];  // this thread's h-quarter (32 f16)
#pragma unroll
  for (int i = 0; i < 16; ++i) hq[i] = 0;
  float c = 0.f;  // cell state for index m (replicated across the quad)

  const int4* __restrict__ xq = h1 + (size_t)b * 1024;  // 8 f16 per step
  int4 xc = xq[0];  // uniform -> s_load

#pragma unroll 1
  for (int ts = 0; ts < 1024; ++ts) {
    int4 xn = xq[(ts + 1) & 1023];  // prefetch (wraps harmlessly at the end)

    // x-part + bias for this thread's final gate
    float bx = bias;
    bx = dot2(wig[0], xc.x, bx);
    bx = dot2(wig[1], xc.y, bx);
    bx = dot2(wig[2], xc.z, bx);
    bx = dot2(wig[3], xc.w, bx);

    // quarter-dots of all 4 gate rows (64 dot2, 4 independent chains)
    float R0 = 0.f, R1 = 0.f, R2 = 0.f, R3 = 0.f;
#pragma unroll
    for (int j = 0; j < 16; ++j) {
      R0 = dot2(w[j], hq[j], R0);
      R1 = dot2(w[16 + j], hq[j], R1);
      R2 = dot2(w[32 + j], hq[j], R2);
      R3 = dot2(w[48 + j], hq[j], R3);
    }
    // transpose-reduce across the quad: thread q ends with gate G's full sum
    float s0 = sel0 ? R0 : R2, s1 = sel0 ? R1 : R3;   // send
    float k0 = sel0 ? R2 : R0, k1 = sel0 ? R3 : R1;   // keep
    float S0 = k0 + swzf<SWZ_X1>(s0);
    float S1 = k1 + swzf<SWZ_X1>(s1);
    float s2 = sel1 ? S0 : S1;
    float k2 = sel1 ? S1 : S0;
    float S = k2 + swzf<SWZ_X2>(s2) + bx;

    // activation: gate G (tanh iff q==1) via 2*sig(2x)-1
    float u = isq1 ? (S + S) : S;
    float sg = fsig(u);
    float act = isq1 ? fmaf(2.f, sg, -1.f) : sg;

    // gather all 4 activated gates into every quad lane
    float v0 = act;
    float v1 = swzf<SWZ_X1>(v0);
    float v2 = swzf<SWZ_X2>(v0);
    float v3 = swzf<SWZ_X2>(v1);
    float p01 = sel0 ? v1 : v0, p23 = sel0 ? v3 : v2;
    float q01 = sel0 ? v0 : v1, q23 = sel0 ? v2 : v3;
    float iv = sel1 ? p23 : p01;
    float fv = sel1 ? p01 : p23;
    float gv = sel1 ? q23 : q01;
    float ov = sel1 ? q01 : q23;

    c = fmaf(fv, c, iv * gv);
    float hx = ov * ftanh_(c);
    if (isq0) sH[ts & 1][m] = (_Float16)hx;  // one writer per index
    __syncthreads();                         // the only barrier per step

    {  // refresh this thread's h-quarter: 4 x ds_read_b128
      const int4* src = (const int4*)(&sH[ts & 1][q * 32]);
      int4 A = src[0], B = src[1], C = src[2], D = src[3];
      hq[0] = A.x; hq[1] = A.y; hq[2] = A.z; hq[3] = A.w;
      hq[4] = B.x; hq[5] = B.y; hq[6] = B.z; hq[7] = B.w;
      hq[8] = C.x; hq[9] = C.y; hq[10] = C.z; hq[11] = C.w;
      hq[12] = D.x; hq[13] = D.y; hq[14] = D.z; hq[15] = D.w;
    }
    xc = xn;
  }

  // Epilogue: out[b] = (h @ Wd1.T + bd1) @ Wd2.T + bd2; h_T is in sH[1].
  if (t < 64) {
    float a = bd1[t];
#pragma unroll
    for (int k = 0; k < 128; ++k)
      a = fmaf(Wd1[t * 128 + k], (float)sH[1][k], a);
    float v = a * Wd2[t];
#pragma unroll
    for (int off = 32; off > 0; off >>= 1) v += __shfl_down(v, off);
    if (t == 0) out[b] = v + bd2[0];
  }
}

extern "C" void kernel_launch(void* const* d_in, const int* in_sizes, int n_in,
                              void* d_out, int out_size, void* d_ws, size_t ws_size,
                              hipStream_t stream) {
  const float* x    = (const float*)d_in[0];
  // d_in[1] is the unused python scalar `data`
  const float* Wih1 = (const float*)d_in[2];
  const float* Whh1 = (const float*)d_in[3];
  const float* bih1 = (const float*)d_in[4];
  const float* bhh1 = (const float*)d_in[5];
  const float* Wih2 = (const float*)d_in[6];
  const float* Whh2 = (const float*)d_in[7];
  const float* bih2 = (const float*)d_in[8];
  const float* bhh2 = (const float*)d_in[9];
  const float* W1   = (const float*)d_in[10];
  const float* b1   = (const float*)d_in[11];
  const float* W2   = (const float*)d_in[12];
  const float* b2   = (const float*)d_in[13];
  float* out = (float*)d_out;

  int4* h1 = (int4*)d_ws;  // 262144 chains x 8 f16 = 4 MB scratch

  lstm1_kernel<<<1024, 256, 0, stream>>>(x, Wih1, Whh1, bih1, bhh1, h1);
  lstm2_kernel<<<256, 512, 0, stream>>>(h1, Wih2, Whh2, bih2, bhh2,
                                        W1, b1, W2, b2, out);
}